// Round 16
// baseline (43.884 us; speedup 1.0000x reference)
//
#include <hip/hip_runtime.h>

// Locally-connected 2d: x[32,16,66,66], w[1,32,16,64,64,9], bias[1,32,64,64]
// out[32,32,64,64] fp32.
//
// R16 = R15 with the staging h-stride fixed (R15 absmax 9.44: used h*72
// float2, correct is h*288 float2 = 576 floats; loaded wrong weights).
// Block = (h, w-pair), 2 waves, 18 KB LDS -> 2048 blocks = 8 independent
// barrier groups/CU (vs R14's 4) at the same 16 waves/CU.
//  - staging: 2 halves x 18 dense float2 (F = tid + 128*i, seg = F/9, q2 = F%9;
//    source float2 idx = seg*18432 + h*288 + wp*9 + q2).
//  - pack/swizzle pair (verified R9-R14): write g=(flat<<6)+(seg>>3) ^ (o^k)&7,
//    short (seg&7); read g=((w2*9+kk)*32+ln)*2+half ^ (ln^kk)&7.
//  - af (x-fragment) prefetch before staging barrier (R14-proven).
// Per (h,w): out[b,o] = GEMM 32x32x144, kflat=kappa*16+c -> 9 MFMAs, no pad.

#define CI_ 16
#define H_  64
#define W_  64
#define XW_ 66

typedef float f32x16 __attribute__((ext_vector_type(16)));
typedef short s16x8  __attribute__((ext_vector_type(8)));

__device__ inline short f2bf(float f) {  // RNE float->bf16
  unsigned u = __builtin_bit_cast(unsigned, f);
  u += 0x7fffu + ((u >> 16) & 1u);
  return (short)(u >> 16);
}

// ---- prep_x: x[b][c][hh][ww] f32 -> xP[hh][ww][b][c] bf16 (verified R8-R14) -
__global__ __launch_bounds__(256) void prep_x(const float* __restrict__ x,
                                              short* __restrict__ xP) {
  const int t = blockIdx.x * 256 + threadIdx.x;  // 66*66*32*2 = 278784 exact
  const int oct = t & 1;
  const int b   = (t >> 1) & 31;
  const int hhww = t >> 6;
  const float* sp = x + ((size_t)b * CI_ + oct * 8) * 4356 + hhww;
  s16x8 v;
#pragma unroll
  for (int e = 0; e < 8; ++e) v[e] = f2bf(sp[(size_t)e * 4356]);
  *(s16x8*)(xP + (size_t)t * 8) = v;
}

// ---- fused main: block = (h, w-pair), 2 waves ------------------------------
__global__ __launch_bounds__(128) void lc2d_fused(
    const short* __restrict__ xP, const float* __restrict__ wt,
    const float* __restrict__ bias, float* __restrict__ out) {
  __shared__ short pw[2 * 9 * 32 * 16];  // [w2][kappa][o][c] + swizzle, 18 KB

  const int d = blockIdx.x;                      // 2048 blocks, XCD-bijective
  const int L = (d & 7) * 256 + (d >> 3);
  const int wp = L & 31;                         // w-pair: w = 2wp, 2wp+1
  const int h  = L >> 5;
  const int tx = threadIdx.x;                    // 0..63
  const int w2 = threadIdx.y;                    // 0..1 (wave id = w in pair)
  const int tid = w2 * 64 + tx;                  // 0..127
  const int ln   = tx & 31;                      // A-row (b) / B-col (o)
  const int half = tx >> 5;                      // c-half: c = half*8 + e
  const int w = wp * 2 + w2;

  // ---- af prefetch (x fragments; consumed after the barrier) ---------------
  const short* ap0 = xP + ln * 16 + half * 8;
  s16x8 af[9];
#pragma unroll
  for (int kk = 0; kk < 9; ++kk) {
    const int i = kk / 3, j = kk - 3 * i;
    af[kk] = *(const s16x8*)(ap0 + (size_t)((h + i) * XW_ + (w + j)) * 512);
  }

  // ---- staging: 2 halves x 18 dense float2 (F = tid + 128*i) ---------------
  // Block slice: 512 segs (o*16+c) x 18 floats (2w x 9k) = 4608 float2.
#pragma unroll
  for (int hf = 0; hf < 2; ++hf) {
    float2 vst[18];
#pragma unroll
    for (int i = 0; i < 18; ++i) {
      const int F = tid + 128 * (hf * 18 + i);   // 0..4607
      const int seg = F / 9;                     // exact (compiler magic-mul)
      const int q2  = F % 9;                     // float2 within 18-float slice
      vst[i] = ((const float2*)wt)[(size_t)seg * 18432 + h * 288 + wp * 9 + q2];
    }
#pragma unroll
    for (int i = 0; i < 18; ++i) {
      const int F = tid + 128 * (hf * 18 + i);
      const int seg = F / 9;
      const int q2  = F % 9;
      const int o  = seg >> 4;
      const int s3 = seg >> 3, s7 = seg & 7;
      const float* vv = (const float*)&vst[i];
#pragma unroll
      for (int e = 0; e < 2; ++e) {
        const int flat = 2 * q2 + e;             // w2f*9 + k, 0..17
        const int k = flat - 9 * (flat / 9);     // exact
        const int g = ((flat << 6) + s3) ^ ((o ^ k) & 7);
        pw[(g << 3) | s7] = f2bf(vv[e]);
      }
    }
  }
  __syncthreads();

  // ---- 9 MFMAs: af from regs, bf from swizzled LDS -------------------------
  f32x16 acc = {0,0,0,0,0,0,0,0,0,0,0,0,0,0,0,0};
#pragma unroll
  for (int kk = 0; kk < 9; ++kk) {
    int g = ((w2 * 9 + kk) * 32 + ln) * 2 + half;
    g ^= (ln ^ kk) & 7;
    const s16x8 bf = *(const s16x8*)(pw + (g << 3));
    acc = __builtin_amdgcn_mfma_f32_32x32x16_bf16(af[kk], bf, acc, 0, 0, 0);
  }

  // ---- epilogue: C/D col(o)=ln, row(b)=(r&3)+8*(r>>2)+4*half (verified) ----
  __syncthreads();                               // pw reads done
  float* tr = (float*)pw;                        // 8 KB of the 18 KB, reuse
#pragma unroll
  for (int r = 0; r < 16; ++r) {
    const int b = (r & 3) + 8 * (r >> 2) + 4 * half;
    tr[(w2 * 32 + b) * 32 + ln] = acc[r];
  }
  __syncthreads();

  const int o = tid & 31;
  const int brow = tid >> 5;                     // 0..3
  const float2 bv = *(const float2*)(bias + (size_t)o * (H_ * W_) + h * W_ + wp * 2);
#pragma unroll
  for (int it = 0; it < 8; ++it) {
    const int b = it * 4 + brow;
    float2 v;
    v.x = tr[(0 * 32 + b) * 32 + o] + bv.x;
    v.y = tr[(1 * 32 + b) * 32 + o] + bv.y;
    *(float2*)(out + ((size_t)b * 32 + o) * (H_ * W_) + h * W_ + wp * 2) = v;
  }
}

// ---- fallback (R7-verified, no workspace): gather MFMA ----------------------
__global__ __launch_bounds__(256, 4) void lc2d_mfma0(
    const float* __restrict__ xs, const float* __restrict__ wt,
    const float* __restrict__ bias, float* __restrict__ out) {
  __shared__ float wlds[8 * 32 * 36];
  const int d = blockIdx.x;
  const int L = (d & 7) * 128 + (d >> 3);
  const int wq = L & 15;
  const int h  = L >> 4;
  const int tx = threadIdx.x;
  const int w2 = threadIdx.y;
  const int ln = tx & 31;
  const int half = tx >> 5;
  const int tid = w2 * 64 + tx;
  const int w = wq * 4 + w2;
  f32x16 acc = {0,0,0,0,0,0,0,0,0,0,0,0,0,0,0,0};
  const int bbase = ln * 36 + w2 * 9;
  size_t abase = (size_t)ln * 69696 + (size_t)h * XW_ + w;

  for (int s = 0; s < 2; ++s) {
    const int c0 = s * 8;
    __syncthreads();
#pragma unroll
    for (int i = 0; i < 9; ++i) {
      const int f4 = tid + i * 256;
      const int cc = f4 / 288;
      const int rem = f4 - cc * 288;
      const int oo = rem / 9;
      const int q = rem - oo * 9;
      const float4* src = (const float4*)wt +
          (((size_t)oo * CI_ + (c0 + cc)) * H_ + h) * 144 + (size_t)wq * 9 + q;
      ((float4*)wlds)[f4] = *src;
    }
    __syncthreads();
#pragma unroll
    for (int cc = 0; cc < 8; ++cc) {
      const int c = c0 + cc;
      const float* ap = xs + abase + (size_t)c * 4356;
      float av[8] = {0,0,0,0,0,0,0,0};
      float bvv[8] = {0,0,0,0,0,0,0,0};
      av[0] = ap[half ? (2 * XW_ + 2) : 0];
      bvv[0] = wlds[cc * 1152 + bbase + (half ? 8 : 0)];
      if (half == 0) {
#pragma unroll
        for (int e = 1; e < 8; ++e) {
          const int i = e / 3, j = e - 3 * i;
          av[e] = ap[i * XW_ + j];
          bvv[e] = wlds[cc * 1152 + bbase + e];
        }
      }
      s16x8 afr, bfr;
#pragma unroll
      for (int e = 0; e < 8; ++e) { afr[e] = f2bf(av[e]); bfr[e] = f2bf(bvv[e]); }
      acc = __builtin_amdgcn_mfma_f32_32x32x16_bf16(afr, bfr, acc, 0, 0, 0);
    }
  }
  const float bvv = bias[((size_t)ln * H_ + h) * W_ + w];
#pragma unroll
  for (int r = 0; r < 16; ++r) {
    const int b = (r & 3) + 8 * (r >> 2) + 4 * half;
    out[(((size_t)b * 32 + ln) * H_ + h) * W_ + w] = acc[r] + bvv;
  }
}

extern "C" void kernel_launch(void* const* d_in, const int* in_sizes, int n_in,
                              void* d_out, int out_size, void* d_ws, size_t ws_size,
                              hipStream_t stream) {
  const float* x    = (const float*)d_in[0];
  const float* wt   = (const float*)d_in[1];
  const float* bias = (const float*)d_in[2];
  float* out = (float*)d_out;

  const size_t xp_bytes = (size_t)66 * 66 * 32 * 16 * sizeof(short);  // 4.46 MB
  if (ws_size >= xp_bytes) {
    short* xP = (short*)d_ws;
    prep_x<<<1089, 256, 0, stream>>>(x, xP);
    lc2d_fused<<<2048, dim3(64, 2, 1), 0, stream>>>(xP, wt, bias, out);
  } else {
    lc2d_mfma0<<<1024, dim3(64, 4, 1), 0, stream>>>(x, wt, bias, out);
  }
}

// Round 18
// 39.950 us; speedup vs baseline: 1.0985x; 1.0985x over previous
//
#include <hip/hip_runtime.h>

// Locally-connected 2d: x[32,16,66,66], w[1,32,16,64,64,9], bias[1,32,64,64]
// out[32,32,64,64] fp32.
//
// R18 = R17 resubmitted verbatim (infra failure; never measured).
// R17 = R12 dataflow (18 staging float4 + 9 af fragments all prefetched before
// the barrier) + __launch_bounds__(256, 2).
// R16 smoking gun: VGPR_Count=72 < ~110 live set, no scratch -> compiler SANK
// the loads (serialized ~36 x ~900cy per block = ~17us/block). min-waves=2
// raises the VGPR cap to 256 so the full prefetch stays in registers and all
// 27 loads pipeline. Occupancy 4->3 blocks/CU is the accepted trade.
// Exact /9 divides (R13 lesson). Swizzle pair verified R9-R16 (absmax .03125).
// Per (h,w): out[b,o] = GEMM 32x32x144, kflat=kappa*16+c -> 9 MFMAs, no pad.

#define CI_ 16
#define H_  64
#define W_  64
#define XW_ 66

typedef float f32x16 __attribute__((ext_vector_type(16)));
typedef short s16x8  __attribute__((ext_vector_type(8)));

__device__ inline short f2bf(float f) {  // RNE float->bf16
  unsigned u = __builtin_bit_cast(unsigned, f);
  u += 0x7fffu + ((u >> 16) & 1u);
  return (short)(u >> 16);
}

// ---- prep_x: x[b][c][hh][ww] f32 -> xP[hh][ww][b][c] bf16 (verified R8-R16) -
__global__ __launch_bounds__(256) void prep_x(const float* __restrict__ x,
                                              short* __restrict__ xP) {
  const int t = blockIdx.x * 256 + threadIdx.x;  // 66*66*32*2 = 278784 exact
  const int oct = t & 1;
  const int b   = (t >> 1) & 31;
  const int hhww = t >> 6;
  const float* sp = x + ((size_t)b * CI_ + oct * 8) * 4356 + hhww;
  s16x8 v;
#pragma unroll
  for (int e = 0; e < 8; ++e) v[e] = f2bf(sp[(size_t)e * 4356]);
  *(s16x8*)(xP + (size_t)t * 8) = v;
}

// ---- fused main: block = (h, w-quad), 4 waves; deep register prefetch ------
__global__ __launch_bounds__(256, 2) void lc2d_fused(
    const short* __restrict__ xP, const float* __restrict__ wt,
    const float* __restrict__ bias, float* __restrict__ out) {
  __shared__ short pw[4 * 9 * 32 * 16];  // [w2][kappa][o][c] + swizzle, 36 KB

  const int d = blockIdx.x;                      // 1024 blocks, XCD-bijective
  const int L = (d & 7) * 128 + (d >> 3);
  const int wq = L & 15;
  const int h  = L >> 4;
  const int tx = threadIdx.x;                    // 0..63
  const int w2 = threadIdx.y;                    // 0..3 (wave id = w in quad)
  const int tid = w2 * 64 + tx;                  // 0..255
  const int ln   = tx & 31;                      // A-row (b) / B-col (o)
  const int half = tx >> 5;                      // c-half: c = half*8 + e
  const int w = wq * 4 + w2;

  // ---- issue af prefetch (x fragments; independent of LDS) -----------------
  const short* ap0 = xP + ln * 16 + half * 8;
  s16x8 af[9];
#pragma unroll
  for (int kk = 0; kk < 9; ++kk) {
    const int i = kk / 3, j = kk - 3 * i;
    af[kk] = *(const s16x8*)(ap0 + (size_t)((h + i) * XW_ + (w + j)) * 512);
  }

  // ---- issue ALL staging loads: dense, 1KB/wave-instr, each float once -----
  float4 vst[18];
#pragma unroll
  for (int i = 0; i < 18; ++i) {
    const int f4 = tid + 256 * i;                // 0..4607
    const int seg = f4 / 9;                      // exact (compiler magic-mul)
    const int q   = f4 % 9;
    vst[i] = ((const float4*)wt)[((size_t)seg * H_ + h) * 144 + wq * 9 + q];
  }

  // ---- pack/scatter into swizzled LDS (verified mapping) -------------------
#pragma unroll
  for (int i = 0; i < 18; ++i) {
    const int f4 = tid + 256 * i;
    const int seg = f4 / 9;
    const int q   = f4 % 9;
    const int o  = seg >> 4;
    const int s3 = seg >> 3, s7 = seg & 7;
    const float* vv = (const float*)&vst[i];
#pragma unroll
    for (int e = 0; e < 4; ++e) {
      const int flat = 4 * q + e;                // w2f*9 + k, 0..35
      const int k = flat - 9 * (flat / 9);       // exact
      const int g = ((flat << 6) + s3) ^ ((o ^ k) & 7);
      pw[(g << 3) | s7] = f2bf(vv[e]);
    }
  }
  __syncthreads();

  // ---- 9 MFMAs: af from regs, bf from swizzled LDS -------------------------
  f32x16 acc = {0,0,0,0,0,0,0,0,0,0,0,0,0,0,0,0};
#pragma unroll
  for (int kk = 0; kk < 9; ++kk) {
    int g = ((w2 * 9 + kk) * 32 + ln) * 2 + half;
    g ^= (ln ^ kk) & 7;
    const s16x8 bf = *(const s16x8*)(pw + (g << 3));
    acc = __builtin_amdgcn_mfma_f32_32x32x16_bf16(af[kk], bf, acc, 0, 0, 0);
  }

  // ---- epilogue: C/D col(o)=ln, row(b)=(r&3)+8*(r>>2)+4*half (verified) ----
  __syncthreads();                               // pw reads done
  float* tr = (float*)pw;                        // 16 KB reuse
#pragma unroll
  for (int r = 0; r < 16; ++r) {
    const int b = (r & 3) + 8 * (r >> 2) + 4 * half;
    tr[(w2 * 32 + b) * 32 + ln] = acc[r];
  }
  __syncthreads();

  const int o = tid & 31;
  const int brow = tid >> 5;                     // 0..7
  const float4 bv = *(const float4*)(bias + ((size_t)o * H_ + h) * W_ + wq * 4);
#pragma unroll
  for (int it = 0; it < 4; ++it) {
    const int b = it * 8 + brow;
    float4 v;
    v.x = tr[(0 * 32 + b) * 32 + o] + bv.x;
    v.y = tr[(1 * 32 + b) * 32 + o] + bv.y;
    v.z = tr[(2 * 32 + b) * 32 + o] + bv.z;
    v.w = tr[(3 * 32 + b) * 32 + o] + bv.w;
    *(float4*)(out + ((size_t)b * 32 + o) * (H_ * W_) + h * W_ + wq * 4) = v;
  }
}

// ---- fallback (R7-verified, no workspace): gather MFMA ----------------------
__global__ __launch_bounds__(256, 4) void lc2d_mfma0(
    const float* __restrict__ xs, const float* __restrict__ wt,
    const float* __restrict__ bias, float* __restrict__ out) {
  __shared__ float wlds[8 * 32 * 36];
  const int d = blockIdx.x;
  const int L = (d & 7) * 128 + (d >> 3);
  const int wq = L & 15;
  const int h  = L >> 4;
  const int tx = threadIdx.x;
  const int w2 = threadIdx.y;
  const int ln = tx & 31;
  const int half = tx >> 5;
  const int tid = w2 * 64 + tx;
  const int w = wq * 4 + w2;
  f32x16 acc = {0,0,0,0,0,0,0,0,0,0,0,0,0,0,0,0};
  const int bbase = ln * 36 + w2 * 9;
  size_t abase = (size_t)ln * 69696 + (size_t)h * XW_ + w;

  for (int s = 0; s < 2; ++s) {
    const int c0 = s * 8;
    __syncthreads();
#pragma unroll
    for (int i = 0; i < 9; ++i) {
      const int f4 = tid + i * 256;
      const int cc = f4 / 288;
      const int rem = f4 - cc * 288;
      const int oo = rem / 9;
      const int q = rem - oo * 9;
      const float4* src = (const float4*)wt +
          (((size_t)oo * CI_ + (c0 + cc)) * H_ + h) * 144 + (size_t)wq * 9 + q;
      ((float4*)wlds)[f4] = *src;
    }
    __syncthreads();
#pragma unroll
    for (int cc = 0; cc < 8; ++cc) {
      const int c = c0 + cc;
      const float* ap = xs + abase + (size_t)c * 4356;
      float av[8] = {0,0,0,0,0,0,0,0};
      float bvv[8] = {0,0,0,0,0,0,0,0};
      av[0] = ap[half ? (2 * XW_ + 2) : 0];
      bvv[0] = wlds[cc * 1152 + bbase + (half ? 8 : 0)];
      if (half == 0) {
#pragma unroll
        for (int e = 1; e < 8; ++e) {
          const int i = e / 3, j = e - 3 * i;
          av[e] = ap[i * XW_ + j];
          bvv[e] = wlds[cc * 1152 + bbase + e];
        }
      }
      s16x8 afr, bfr;
#pragma unroll
      for (int e = 0; e < 8; ++e) { afr[e] = f2bf(av[e]); bfr[e] = f2bf(bvv[e]); }
      acc = __builtin_amdgcn_mfma_f32_32x32x16_bf16(afr, bfr, acc, 0, 0, 0);
    }
  }
  const float bvv = bias[((size_t)ln * H_ + h) * W_ + w];
#pragma unroll
  for (int r = 0; r < 16; ++r) {
    const int b = (r & 3) + 8 * (r >> 2) + 4 * half;
    out[(((size_t)b * 32 + ln) * H_ + h) * W_ + w] = acc[r] + bvv;
  }
}

extern "C" void kernel_launch(void* const* d_in, const int* in_sizes, int n_in,
                              void* d_out, int out_size, void* d_ws, size_t ws_size,
                              hipStream_t stream) {
  const float* x    = (const float*)d_in[0];
  const float* wt   = (const float*)d_in[1];
  const float* bias = (const float*)d_in[2];
  float* out = (float*)d_out;

  const size_t xp_bytes = (size_t)66 * 66 * 32 * 16 * sizeof(short);  // 4.46 MB
  if (ws_size >= xp_bytes) {
    short* xP = (short*)d_ws;
    prep_x<<<1089, 256, 0, stream>>>(x, xP);
    lc2d_fused<<<1024, dim3(64, 4, 1), 0, stream>>>(xP, wt, bias, out);
  } else {
    lc2d_mfma0<<<1024, dim3(64, 4, 1), 0, stream>>>(x, wt, bias, out);
  }
}

// Round 19
// 39.621 us; speedup vs baseline: 1.1076x; 1.0083x over previous
//
#include <hip/hip_runtime.h>

// Locally-connected 2d: x[32,16,66,66], w[1,32,16,64,64,9], bias[1,32,64,64]
// out[32,32,64,64] fp32.
//
// R19: register-free weight staging via global_load_lds (dwordx4).
// R9-R18 lesson: every VGPR-staged variant lands ~39-48us because the compiler
// sinks the staging loads (R16: VGPR=72 < live set, no spill) -> ~18 serialized
// long-latency loads/thread. global_load_lds has NO VGPR dest -> cannot be
// sunk; all 18 issues/thread stream with only vmcnt tracking.
// LDS dest is linear (base + lane*16), so the PACKED layout is realized by
// permuting the per-lane GLOBAL address (guide m173 pattern):
//   granule G = i*256+tid -> segL = G/9 = c*32+o (LDS [c][o][w2*9+k] fp32,
//   72 KB static), q = G%9; source float4 = (o*16+c)*9216 + h*144 + wq*9 + q.
// B-fragment consume: 8 ds_read_b32 per MFMA off ONE base, offsets immediate
// (e*1152 + kk dwords); lane stride 36 dw = 8-way bank alias (known cost),
// f2bf in registers. A (x) fragments: af[9] register prefetch (R14-proven).
// Epilogue reuses wlin as the transpose buffer.
// Per (h,w): out[b,o] = GEMM 32x32x144, kflat=kappa*16+c -> 9 MFMAs, no pad.

#define CI_ 16
#define H_  64
#define W_  64
#define XW_ 66

typedef float f32x16 __attribute__((ext_vector_type(16)));
typedef short s16x8  __attribute__((ext_vector_type(8)));

__device__ inline short f2bf(float f) {  // RNE float->bf16
  unsigned u = __builtin_bit_cast(unsigned, f);
  u += 0x7fffu + ((u >> 16) & 1u);
  return (short)(u >> 16);
}

__device__ inline void gload_lds16(const float* g, void* l) {
  __builtin_amdgcn_global_load_lds(
      (const __attribute__((address_space(1))) void*)g,
      (__attribute__((address_space(3))) void*)l, 16, 0, 0);
}

// ---- prep_x: x[b][c][hh][ww] f32 -> xP[hh][ww][b][c] bf16 (verified R8-R18) -
__global__ __launch_bounds__(256) void prep_x(const float* __restrict__ x,
                                              short* __restrict__ xP) {
  const int t = blockIdx.x * 256 + threadIdx.x;  // 66*66*32*2 = 278784 exact
  const int oct = t & 1;
  const int b   = (t >> 1) & 31;
  const int hhww = t >> 6;
  const float* sp = x + ((size_t)b * CI_ + oct * 8) * 4356 + hhww;
  s16x8 v;
#pragma unroll
  for (int e = 0; e < 8; ++e) v[e] = f2bf(sp[(size_t)e * 4356]);
  *(s16x8*)(xP + (size_t)t * 8) = v;
}

// ---- fused main: block = (h, w-quad), 4 waves; LDS-direct staging ----------
__global__ __launch_bounds__(256) void lc2d_fused(
    const short* __restrict__ xP, const float* __restrict__ wt,
    const float* __restrict__ bias, float* __restrict__ out) {
  __shared__ float wlin[16 * 32 * 36];  // [c][o][w2*9+k] fp32 = 72 KB

  const int d = blockIdx.x;                      // 1024 blocks, XCD-bijective
  const int L = (d & 7) * 128 + (d >> 3);
  const int wq = L & 15;
  const int h  = L >> 4;
  const int tx = threadIdx.x;                    // 0..63
  const int w2 = threadIdx.y;                    // 0..3 (wave id = w in quad)
  const int tid = w2 * 64 + tx;                  // 0..255
  const int ln   = tx & 31;                      // A-row (b) / B-col (o)
  const int half = tx >> 5;                      // c-half: c = half*8 + e
  const int w = wq * 4 + w2;

  // ---- af prefetch (x fragments; normal loads, consumed after barrier) -----
  const short* ap0 = xP + ln * 16 + half * 8;
  s16x8 af[9];
#pragma unroll
  for (int kk = 0; kk < 9; ++kk) {
    const int i = kk / 3, j = kk - 3 * i;
    af[kk] = *(const s16x8*)(ap0 + (size_t)((h + i) * XW_ + (w + j)) * 512);
  }

  // ---- staging: 18 global_load_lds dwordx4 per thread (no VGPR dest) -------
  // Lane l of wave w2, issue i -> LDS granule i*256 + w2*64 + l (= G for
  // tid = w2*64+l). Source decoded so LDS layout = [c][o][w2f*9+k] fp32.
#pragma unroll
  for (int i = 0; i < 18; ++i) {
    const int G = i * 256 + tid;                 // granule 0..4607
    const int segL = G / 9;                      // c*32 + o (exact magic-mul)
    const int q    = G - 9 * segL;
    const int o = segL & 31, c = segL >> 5;
    const float* src = wt +
        (((size_t)(o * 16 + c) * 9216 + (size_t)h * 144 + wq * 9 + q) << 2);
    gload_lds16(src, (char*)wlin + (size_t)(i * 256 + w2 * 64) * 16);
  }
  __syncthreads();  // compiler emits s_waitcnt vmcnt(0) + barrier

  // ---- 9 MFMAs: af from regs, bf gathered from wlin (imm-offset b32) -------
  f32x16 acc = {0,0,0,0,0,0,0,0,0,0,0,0,0,0,0,0};
  const int bbase = half * 9216 + ln * 36 + w2 * 9;  // dword base, one v-addr
#pragma unroll
  for (int kk = 0; kk < 9; ++kk) {
    s16x8 bf;
#pragma unroll
    for (int e = 0; e < 8; ++e) {
      bf[e] = f2bf(wlin[bbase + e * 1152 + kk]);  // offset imm = (e*1152+kk)*4 B
    }
    acc = __builtin_amdgcn_mfma_f32_32x32x16_bf16(af[kk], bf, acc, 0, 0, 0);
  }

  // ---- epilogue: C/D col(o)=ln, row(b)=(r&3)+8*(r>>2)+4*half (verified) ----
  __syncthreads();                               // wlin reads done
  float* tr = (float*)wlin;                      // 16 KB reuse
#pragma unroll
  for (int r = 0; r < 16; ++r) {
    const int b = (r & 3) + 8 * (r >> 2) + 4 * half;
    tr[(w2 * 32 + b) * 32 + ln] = acc[r];
  }
  __syncthreads();

  const int o = tid & 31;
  const int brow = tid >> 5;                     // 0..7
  const float4 bv = *(const float4*)(bias + ((size_t)o * H_ + h) * W_ + wq * 4);
#pragma unroll
  for (int it = 0; it < 4; ++it) {
    const int b = it * 8 + brow;
    float4 v;
    v.x = tr[(0 * 32 + b) * 32 + o] + bv.x;
    v.y = tr[(1 * 32 + b) * 32 + o] + bv.y;
    v.z = tr[(2 * 32 + b) * 32 + o] + bv.z;
    v.w = tr[(3 * 32 + b) * 32 + o] + bv.w;
    *(float4*)(out + ((size_t)b * 32 + o) * (H_ * W_) + h * W_ + wq * 4) = v;
  }
}

// ---- fallback (R7-verified, no workspace): gather MFMA ----------------------
__global__ __launch_bounds__(256, 4) void lc2d_mfma0(
    const float* __restrict__ xs, const float* __restrict__ wt,
    const float* __restrict__ bias, float* __restrict__ out) {
  __shared__ float wlds[8 * 32 * 36];
  const int d = blockIdx.x;
  const int L = (d & 7) * 128 + (d >> 3);
  const int wq = L & 15;
  const int h  = L >> 4;
  const int tx = threadIdx.x;
  const int w2 = threadIdx.y;
  const int ln = tx & 31;
  const int half = tx >> 5;
  const int tid = w2 * 64 + tx;
  const int w = wq * 4 + w2;
  f32x16 acc = {0,0,0,0,0,0,0,0,0,0,0,0,0,0,0,0};
  const int bbase = ln * 36 + w2 * 9;
  size_t abase = (size_t)ln * 69696 + (size_t)h * XW_ + w;

  for (int s = 0; s < 2; ++s) {
    const int c0 = s * 8;
    __syncthreads();
#pragma unroll
    for (int i = 0; i < 9; ++i) {
      const int f4 = tid + i * 256;
      const int cc = f4 / 288;
      const int rem = f4 - cc * 288;
      const int oo = rem / 9;
      const int q = rem - oo * 9;
      const float4* src = (const float4*)wt +
          (((size_t)oo * CI_ + (c0 + cc)) * H_ + h) * 144 + (size_t)wq * 9 + q;
      ((float4*)wlds)[f4] = *src;
    }
    __syncthreads();
#pragma unroll
    for (int cc = 0; cc < 8; ++cc) {
      const int c = c0 + cc;
      const float* ap = xs + abase + (size_t)c * 4356;
      float av[8] = {0,0,0,0,0,0,0,0};
      float bvv[8] = {0,0,0,0,0,0,0,0};
      av[0] = ap[half ? (2 * XW_ + 2) : 0];
      bvv[0] = wlds[cc * 1152 + bbase + (half ? 8 : 0)];
      if (half == 0) {
#pragma unroll
        for (int e = 1; e < 8; ++e) {
          const int i = e / 3, j = e - 3 * i;
          av[e] = ap[i * XW_ + j];
          bvv[e] = wlds[cc * 1152 + bbase + e];
        }
      }
      s16x8 afr, bfr;
#pragma unroll
      for (int e = 0; e < 8; ++e) { afr[e] = f2bf(av[e]); bfr[e] = f2bf(bvv[e]); }
      acc = __builtin_amdgcn_mfma_f32_32x32x16_bf16(afr, bfr, acc, 0, 0, 0);
    }
  }
  const float bvv = bias[((size_t)ln * H_ + h) * W_ + w];
#pragma unroll
  for (int r = 0; r < 16; ++r) {
    const int b = (r & 3) + 8 * (r >> 2) + 4 * half;
    out[(((size_t)b * 32 + ln) * H_ + h) * W_ + w] = acc[r] + bvv;
  }
}

extern "C" void kernel_launch(void* const* d_in, const int* in_sizes, int n_in,
                              void* d_out, int out_size, void* d_ws, size_t ws_size,
                              hipStream_t stream) {
  const float* x    = (const float*)d_in[0];
  const float* wt   = (const float*)d_in[1];
  const float* bias = (const float*)d_in[2];
  float* out = (float*)d_out;

  const size_t xp_bytes = (size_t)66 * 66 * 32 * 16 * sizeof(short);  // 4.46 MB
  if (ws_size >= xp_bytes) {
    short* xP = (short*)d_ws;
    prep_x<<<1089, 256, 0, stream>>>(x, xP);
    lc2d_fused<<<1024, dim3(64, 4, 1), 0, stream>>>(xP, wt, bias, out);
  } else {
    lc2d_mfma0<<<1024, dim3(64, 4, 1), 0, stream>>>(x, wt, bias, out);
  }
}